// Round 8
// baseline (2884.976 us; speedup 1.0000x reference)
//
#include <hip/hip_runtime.h>
#include <hip/hip_bf16.h>
#include <stdint.h>
#include <stddef.h>

// LSTM: T=512, B=64, I=512, H=512.
// Phase 1: xproj GEMM (bf16 MFMA), output re-laid as [t][j=32][row=64][g=4][c=16].
// Phase 2: 128 independent waves (32 col-groups x 4 row-groups), 64-thr WGs.
//          R8: ONE-RT tag-in-band handshake (h word = bf16 | step<<16, fire-and-
//          forget sc0 sc1 stores; consumer validates per 16B chunk and re-loads
//          ONLY pending chunks -- R7's regression was all-or-nothing 512B/lane
//          retry). Wh lives in LDS (64KB, staged once, swizzled) -- R6/R7 were
//          re-fetching 64KB/step from L2 (slice is 2x L1).

#define T_STEPS 512
#define BATCH   64
#define HDIM    512

using short8 = __attribute__((ext_vector_type(8))) short;  // 8 bf16 (4 VGPR) MFMA operand
using f32x4  = __attribute__((ext_vector_type(4))) float;  // MFMA accumulator
using int4v  = __attribute__((ext_vector_type(4))) int;

__device__ __forceinline__ void gload_lds16(const void* g, void* l) {
  __builtin_amdgcn_global_load_lds((const __attribute__((address_space(1))) void*)g,
                                   (__attribute__((address_space(3))) void*)l, 16, 0, 0);
}
__device__ __forceinline__ float sigf(float x) { return 1.0f / (1.0f + __expf(-x)); }
__device__ __forceinline__ float tanh_fast(float x) {
  x = fminf(fmaxf(x, -15.0f), 15.0f);
  float e = __expf(2.0f * x);
  return (e - 1.0f) / (e + 1.0f);
}
__device__ __forceinline__ short bfb(float f) {
  __hip_bfloat16 h = __float2bfloat16(f);
  short s; __builtin_memcpy(&s, &h, 2); return s;
}
__device__ __forceinline__ unsigned bfbits(float f) {
  __hip_bfloat16 h = __float2bfloat16(f);
  unsigned short s; __builtin_memcpy(&s, &h, 2); return (unsigned)s;
}
__device__ __forceinline__ float bf2f(unsigned u) {  // bf16 bits (low 16) -> f32
  return __builtin_bit_cast(float, u << 16);
}

// ---------------- prep: build Wx_bt/Wh_bt [2048][512] bf16, bias[2048], zero hbuf32
__global__ __launch_bounds__(256) void k_prep(
    const float* __restrict__ Wf, const float* __restrict__ bf_,
    const float* __restrict__ Wi, const float* __restrict__ bi,
    const float* __restrict__ Wg, const float* __restrict__ bg,
    const float* __restrict__ Wo, const float* __restrict__ bo,
    __hip_bfloat16* __restrict__ wxbt, __hip_bfloat16* __restrict__ whbt,
    float* __restrict__ bias, unsigned* __restrict__ hbuf32)
{
  int idx = blockIdx.x * 256 + threadIdx.x;   // 4096 blocks -> 1,048,576 = 2048*512
  int row = idx >> 9;                          // 0..2047 (gate-major)
  int k   = idx & 511;
  int g = row >> 9, r = row & 511;
  const float* W = (g == 0) ? Wf : (g == 1) ? Wi : (g == 2) ? Wg : Wo;
  const float* B = (g == 0) ? bf_ : (g == 1) ? bi : (g == 2) ? bg : bo;
  wxbt[(size_t)row * 512 + k] = __float2bfloat16(W[(size_t)r * 1024 + k]);
  whbt[(size_t)row * 512 + k] = __float2bfloat16(W[(size_t)r * 1024 + 512 + k]);
  if (k == 0) bias[row] = B[r];
  if (idx < 2 * BATCH * HDIM) hbuf32[idx] = 0u;   // h=0 (bf16 0), tag=0 (=step 0)
}

// ---------------- convert x to bf16, 8 elems/thread
__global__ __launch_bounds__(256) void k_convx(const float* __restrict__ x,
                                               __hip_bfloat16* __restrict__ xbf)
{
  int idx = blockIdx.x * 256 + threadIdx.x;    // 8192 blocks
  const float4* p = (const float4*)x + (size_t)idx * 2;
  float4 a = p[0], b = p[1];
  short8 o;
  o[0]=bfb(a.x); o[1]=bfb(a.y); o[2]=bfb(a.z); o[3]=bfb(a.w);
  o[4]=bfb(b.x); o[5]=bfb(b.y); o[6]=bfb(b.z); o[7]=bfb(b.w);
  *(short8*)((short*)xbf + (size_t)idx * 8) = o;
}

// ---------------- phase 1 GEMM: [32768,512] x [512 -> 2048] (B^T layout), +bias
// Output re-laid: xproj[t][j][row][g][c]  (t=512, j=32 colgroups, row=64, g=4, c=16)
__global__ __launch_bounds__(256) void k_xproj(
    const __hip_bfloat16* __restrict__ xbf,   // [32768][512]
    const __hip_bfloat16* __restrict__ wxbt,  // [2048][512]
    const float* __restrict__ bias,           // [2048]
    __hip_bfloat16* __restrict__ xproj)       // [512][32][64][4][16]
{
  __shared__ __align__(16) short aT[128 * 64];
  __shared__ __align__(16) short bT[128 * 64];
  const int tid = threadIdx.x, lane = tid & 63, wave = tid >> 6;
  const int m0 = blockIdx.y * 128, n0 = blockIdx.x * 128;
  const int wr = wave >> 1, wc = wave & 1;

  f32x4 acc[4][4] = {};

  for (int s = 0; s < 8; ++s) {               // K=512, BK=64
    __syncthreads();
    const int kbyte = s * 128;
#pragma unroll
    for (int it = 0; it < 4; ++it) {
      int flat = it * 256 + tid;
      int row = flat >> 3, gr = flat & 7;
      int sgr = gr ^ (row & 7);
      const char* ga = (const char*)xbf  + (size_t)(m0 + row) * 1024 + kbyte + sgr * 16;
      const char* gb = (const char*)wxbt + (size_t)(n0 + row) * 1024 + kbyte + sgr * 16;
      gload_lds16(ga, (char*)aT + (it * 256 + wave * 64) * 16);
      gload_lds16(gb, (char*)bT + (it * 256 + wave * 64) * 16);
    }
    __syncthreads();
#pragma unroll
    for (int kk2 = 0; kk2 < 2; ++kk2) {
      short8 af[4], bfr[4];
#pragma unroll
      for (int mt = 0; mt < 4; ++mt) {
        int r = wr * 64 + mt * 16 + (lane & 15);
        int g = (kk2 * 4 + (lane >> 4)) ^ (r & 7);
        af[mt] = *(const short8*)((const char*)aT + r * 128 + g * 16);
      }
#pragma unroll
      for (int nt = 0; nt < 4; ++nt) {
        int r = wc * 64 + nt * 16 + (lane & 15);
        int g = (kk2 * 4 + (lane >> 4)) ^ (r & 7);
        bfr[nt] = *(const short8*)((const char*)bT + r * 128 + g * 16);
      }
#pragma unroll
      for (int mt = 0; mt < 4; ++mt)
#pragma unroll
        for (int nt = 0; nt < 4; ++nt)
          acc[mt][nt] = __builtin_amdgcn_mfma_f32_16x16x32_bf16(af[mt], bfr[nt], acc[mt][nt], 0, 0, 0);
    }
  }
  // epilogue: + bias, store bf16 into re-laid layout. C: col=lane&15, row=(lane>>4)*4+i
#pragma unroll
  for (int nt = 0; nt < 4; ++nt) {
    int n = n0 + wc * 64 + nt * 16 + (lane & 15);
    float bv = bias[n];
    int j2 = (n >> 4) & 31, g2 = n >> 9, c2 = n & 15;
#pragma unroll
    for (int mt = 0; mt < 4; ++mt)
#pragma unroll
      for (int i = 0; i < 4; ++i) {
        int m = m0 + wr * 64 + mt * 16 + (lane >> 4) * 4 + i;
        int tt = m >> 6, rr = m & 63;
        xproj[(((size_t)tt * 32 + j2) * 64 + rr) * 64 + g2 * 16 + c2] =
            __float2bfloat16(acc[mt][nt][i] + bv);
      }
  }
}

// ---------------- phase 2: 128 independent waves (64-thread WGs).
// Wave bid: j = bid>>2 owns h-cols [j*16,j*16+16); w = bid&3 owns batch rows
// [w*16,w*16+16). hbuf32[2][64][512]: word = bf16(h) | tag<<16; consumer at step
// t validates buf[t&1] per 16B chunk (stale tags in {0, t-2} < t; AND-high == t
// iff all 4 words fresh) and re-loads only pending chunks. Wh in LDS (swizzled).
__global__ __launch_bounds__(64, 1) void k_recur(
    const __hip_bfloat16* __restrict__ xproj, // [512][32][64][4][16]
    const __hip_bfloat16* __restrict__ whbt,  // [2048][512]
    unsigned* __restrict__ hbuf32,            // [2][64][512] tagged words
    float* __restrict__ out)                  // outputs | hx | cx
{
  __shared__ __align__(16) short wlds[64 * 512];   // 64 KB: row = g*16+c, swizzled
  const int lane = threadIdx.x;
  const int bid  = blockIdx.x;                 // 0..127
  const int j = bid >> 2, w = bid & 3;
  const int hc0 = j * 16, col = lane & 15, q = lane >> 4, mrow = q * 4;

  // ---- stage Wh slice into LDS, once. LDS[row][gr] = whbt_row(row)[gr ^ ((row&15)<<2)]
  // (involution; read side XORs the same) -- reads become a permutation of linear.
  for (int it = 0; it < 64; ++it) {            // row = it, granule = lane
    int sgr = lane ^ ((it & 15) << 2);
    const char* gsrc = (const char*)whbt +
        ((size_t)((it >> 4) * 512 + hc0 + (it & 15))) * 1024 + sgr * 16;
    gload_lds16(gsrc, (char*)wlds + it * 1024);   // uniform base; HW adds lane*16
  }
  asm volatile("s_waitcnt vmcnt(0)" ::: "memory");
  __builtin_amdgcn_sched_barrier(0);           // no LDS read above the staging drain

  float c_state[4] = {0.f, 0.f, 0.f, 0.f};
  float* out_hx = out + (size_t)T_STEPS * BATCH * HDIM;
  float* out_cx = out_hx + BATCH * HDIM;

  // per-lane h chunk base: row = w*16 + (lane&15), words q*8.. (byte q*32)
  const char* hbl = (const char*)hbuf32 +
                    ((size_t)(w * 16 + (lane & 15)) * 512 + q * 8) * 4;
  // per-lane LDS read base: row = gg*16+col -> byte (gg*16+col)*1024 + ((kk^col)<<6) + (q<<4)
  const char* lbase = (const char*)wlds + (size_t)col * 1024 + (q << 4);

  for (int t = 0; t < T_STEPS; ++t) {
    const int cur = t & 1;
    // ---- xp loads pre-poll (drained by the poll's vmcnt(0))
    const char* xpb = (const char*)xproj +
        (((size_t)t * 32 + j) * 4096 + (size_t)(w * 16 + mrow) * 64 + col) * 2;
    unsigned xpu[4][4];
#pragma unroll
    for (int g = 0; g < 4; ++g)
#pragma unroll
      for (int i = 0; i < 4; ++i) {
        const void* p = xpb + i * 128 + g * 32;
        asm volatile("global_load_ushort %0, %1, off"
                     : "=v"(xpu[g][i]) : "v"(p));
      }

    // ---- poll-and-load h^t: per-chunk tag validation, pending-only retry
    const char* hb = hbl + (size_t)cur * (BATCH * HDIM * 4);
    int4v raw[32];
    unsigned done = 0u;
    while (done != 0xffffffffu) {
#pragma unroll
      for (int ii = 0; ii < 32; ++ii) {
        if (!(done & (1u << ii))) {
          const void* p = hb + (size_t)(ii >> 1) * 128 + (ii & 1) * 16;
          asm volatile("global_load_dwordx4 %0, %1, off sc0 sc1"
                       : "=v"(raw[ii]) : "v"(p));
        }
      }
      asm volatile("s_waitcnt vmcnt(0)" ::: "memory");
      __builtin_amdgcn_sched_barrier(0);   // rule #18: no tag check above the drain
#pragma unroll
      for (int ii = 0; ii < 32; ++ii) {
        if (!(done & (1u << ii))) {
          unsigned a = (unsigned)raw[ii][0] & (unsigned)raw[ii][1]
                     & (unsigned)raw[ii][2] & (unsigned)raw[ii][3];
          if ((a >> 16) == (unsigned)t) done |= (1u << ii);
        }
      }
    }
    __builtin_amdgcn_sched_barrier(0);

    // ---- unpack tagged words -> A fragments; B from LDS; MFMA
    f32x4 acc[4] = {};
#pragma unroll
    for (int kk = 0; kk < 16; ++kk) {
      int4v afw;
      afw[0] = (raw[2*kk][0]   & 0xffff) | (raw[2*kk][1]   << 16);
      afw[1] = (raw[2*kk][2]   & 0xffff) | (raw[2*kk][3]   << 16);
      afw[2] = (raw[2*kk+1][0] & 0xffff) | (raw[2*kk+1][1] << 16);
      afw[3] = (raw[2*kk+1][2] & 0xffff) | (raw[2*kk+1][3] << 16);
      short8 af = __builtin_bit_cast(short8, afw);
      const char* lk = lbase + ((kk ^ col) << 6);
#pragma unroll
      for (int gg = 0; gg < 4; ++gg) {
        short8 bw = *(const short8*)(lk + gg * 16384);
        acc[gg] = __builtin_amdgcn_mfma_f32_16x16x32_bf16(af, bw, acc[gg], 0, 0, 0);
      }
    }

    // ---- epilogue: gates, state update
    float hnv[4], cnv[4];
#pragma unroll
    for (int i = 0; i < 4; ++i) {
      float pf = acc[0][i] + bf2f(xpu[0][i]);
      float pi = acc[1][i] + bf2f(xpu[1][i]);
      float pg = acc[2][i] + bf2f(xpu[2][i]);
      float po = acc[3][i] + bf2f(xpu[3][i]);
      float fg = sigf(pf), ig = sigf(pi), gg2 = tanh_fast(pg), og = sigf(po);
      float cn = fg * c_state[i] + ig * gg2;
      c_state[i] = cn;
      cnv[i] = cn;
      hnv[i] = og * tanh_fast(cn);
    }
    // ---- tagged h stores, fire-and-forget (no drain, no flag)
    if (t < T_STEPS - 1) {
      char* hnxt = (char*)hbuf32 + (size_t)(cur ^ 1) * (BATCH * HDIM * 4) +
                   ((size_t)(w * 16 + mrow) * 512 + hc0 + col) * 4;
      unsigned tag = ((unsigned)(t + 1)) << 16;
#pragma unroll
      for (int i = 0; i < 4; ++i) {
        unsigned word = bfbits(hnv[i]) | tag;
        void* p = hnxt + (size_t)i * 2048;
        asm volatile("global_store_dword %0, %1, off sc0 sc1"
                     :: "v"(p), "v"(word));
      }
    }
    // ---- out stores (plain; drained implicitly later)
    float* outb = out + ((size_t)t * BATCH + w * 16 + mrow) * HDIM + hc0 + col;
#pragma unroll
    for (int i = 0; i < 4; ++i) outb[(size_t)i * HDIM] = hnv[i];
    if (t == T_STEPS - 1) {
#pragma unroll
      for (int i = 0; i < 4; ++i) {
        out_hx[(size_t)(w * 16 + mrow + i) * HDIM + hc0 + col] = hnv[i];
        out_cx[(size_t)(w * 16 + mrow + i) * HDIM + hc0 + col] = cnv[i];
      }
    }
  }
}

extern "C" void kernel_launch(void* const* d_in, const int* in_sizes, int n_in,
                              void* d_out, int out_size, void* d_ws, size_t ws_size,
                              hipStream_t stream) {
  const float* x   = (const float*)d_in[0];
  const float* Wf  = (const float*)d_in[1];
  const float* bf_ = (const float*)d_in[2];
  const float* Wi  = (const float*)d_in[3];
  const float* bi  = (const float*)d_in[4];
  const float* Wg  = (const float*)d_in[5];
  const float* bg  = (const float*)d_in[6];
  const float* Wo  = (const float*)d_in[7];
  const float* bo  = (const float*)d_in[8];

  char* ws = (char*)d_ws;
  __hip_bfloat16* xbf   = (__hip_bfloat16*)(ws);                 // 33,554,432 B
  __hip_bfloat16* wxbt  = (__hip_bfloat16*)(ws + 33554432);      //  2,097,152 B
  __hip_bfloat16* whbt  = (__hip_bfloat16*)(ws + 35651584);      //  2,097,152 B
  float*          bias  = (float*)         (ws + 37748736);      //      8,192 B
  __hip_bfloat16* xproj = (__hip_bfloat16*)(ws + 37756928);      // 134,217,728 B
  unsigned*       hbuf32= (unsigned*)      (ws + 171974656);     //    262,144 B

  k_prep <<<4096, 256, 0, stream>>>(Wf, bf_, Wi, bi, Wg, bg, Wo, bo,
                                    wxbt, whbt, bias, hbuf32);
  k_convx<<<8192, 256, 0, stream>>>(x, xbf);
  k_xproj<<<dim3(16, 256), 256, 0, stream>>>(xbf, wxbt, bias, xproj);
  k_recur<<<128, 64, 0, stream>>>(xproj, whbt, hbuf32, (float*)d_out);
}

// Round 9
// 2263.990 us; speedup vs baseline: 1.2743x; 1.2743x over previous
//
#include <hip/hip_runtime.h>
#include <hip/hip_bf16.h>
#include <stdint.h>
#include <stddef.h>

// LSTM: T=512, B=64, I=512, H=512.
// Phase 1: xproj GEMM (bf16 MFMA), output re-laid as [t][j=32][row=64][g=4][c=16].
// Phase 2: 128 independent waves (32 col-groups x 4 row-groups), 64-thr WGs.
//   R9 = R6 skeleton + (1) Wh in LDS w/ CORRECT swizzle (granule ^= row&7 ->
//   8 lanes per bank-group, conflict-free; R8's <<6 variant was 8-way),
//   (2) tagged h (bf16|step<<16) so producers publish flag with NO drain
//   (tags catch any store reordering), (3) packed flag poll (lanes 0-7,
//   dwordx4: 8 loads/pass vs 64), (4) bulk h load + single AND-validate,
//   chunked retry only on rare miss. No asm-pinned arrays, no XCD homing.

#define T_STEPS 512
#define BATCH   64
#define HDIM    512

using short8 = __attribute__((ext_vector_type(8))) short;  // 8 bf16 (4 VGPR) MFMA operand
using f32x4  = __attribute__((ext_vector_type(4))) float;  // MFMA accumulator
using int4v  = __attribute__((ext_vector_type(4))) int;

__device__ __forceinline__ void gload_lds16(const void* g, void* l) {
  __builtin_amdgcn_global_load_lds((const __attribute__((address_space(1))) void*)g,
                                   (__attribute__((address_space(3))) void*)l, 16, 0, 0);
}
__device__ __forceinline__ float sigf(float x) { return 1.0f / (1.0f + __expf(-x)); }
__device__ __forceinline__ float tanh_fast(float x) {
  x = fminf(fmaxf(x, -15.0f), 15.0f);
  float e = __expf(2.0f * x);
  return (e - 1.0f) / (e + 1.0f);
}
__device__ __forceinline__ short bfb(float f) {
  __hip_bfloat16 h = __float2bfloat16(f);
  short s; __builtin_memcpy(&s, &h, 2); return s;
}
__device__ __forceinline__ unsigned bfbits(float f) {
  __hip_bfloat16 h = __float2bfloat16(f);
  unsigned short s; __builtin_memcpy(&s, &h, 2); return (unsigned)s;
}
__device__ __forceinline__ float bf2f(unsigned u) {  // bf16 bits (low 16) -> f32
  return __builtin_bit_cast(float, u << 16);
}

// ---------------- prep: build Wx_bt/Wh_bt [2048][512] bf16, bias[2048], zero hbuf32+flags
__global__ __launch_bounds__(256) void k_prep(
    const float* __restrict__ Wf, const float* __restrict__ bf_,
    const float* __restrict__ Wi, const float* __restrict__ bi,
    const float* __restrict__ Wg, const float* __restrict__ bg,
    const float* __restrict__ Wo, const float* __restrict__ bo,
    __hip_bfloat16* __restrict__ wxbt, __hip_bfloat16* __restrict__ whbt,
    float* __restrict__ bias, unsigned* __restrict__ hbuf32, int* __restrict__ flags)
{
  int idx = blockIdx.x * 256 + threadIdx.x;   // 4096 blocks -> 1,048,576 = 2048*512
  int row = idx >> 9;                          // 0..2047 (gate-major)
  int k   = idx & 511;
  int g = row >> 9, r = row & 511;
  const float* W = (g == 0) ? Wf : (g == 1) ? Wi : (g == 2) ? Wg : Wo;
  const float* B = (g == 0) ? bf_ : (g == 1) ? bi : (g == 2) ? bg : bo;
  wxbt[(size_t)row * 512 + k] = __float2bfloat16(W[(size_t)r * 1024 + k]);
  whbt[(size_t)row * 512 + k] = __float2bfloat16(W[(size_t)r * 1024 + 512 + k]);
  if (k == 0) bias[row] = B[r];
  if (idx < 2 * BATCH * HDIM) hbuf32[idx] = 0u;   // h=0 (bf16 0), tag=0 (=step 0)
  if (idx < 128) flags[idx] = 0;
}

// ---------------- convert x to bf16, 8 elems/thread
__global__ __launch_bounds__(256) void k_convx(const float* __restrict__ x,
                                               __hip_bfloat16* __restrict__ xbf)
{
  int idx = blockIdx.x * 256 + threadIdx.x;    // 8192 blocks
  const float4* p = (const float4*)x + (size_t)idx * 2;
  float4 a = p[0], b = p[1];
  short8 o;
  o[0]=bfb(a.x); o[1]=bfb(a.y); o[2]=bfb(a.z); o[3]=bfb(a.w);
  o[4]=bfb(b.x); o[5]=bfb(b.y); o[6]=bfb(b.z); o[7]=bfb(b.w);
  *(short8*)((short*)xbf + (size_t)idx * 8) = o;
}

// ---------------- phase 1 GEMM: [32768,512] x [512 -> 2048] (B^T layout), +bias
// Output re-laid: xproj[t][j][row][g][c]  (t=512, j=32 colgroups, row=64, g=4, c=16)
__global__ __launch_bounds__(256) void k_xproj(
    const __hip_bfloat16* __restrict__ xbf,   // [32768][512]
    const __hip_bfloat16* __restrict__ wxbt,  // [2048][512]
    const float* __restrict__ bias,           // [2048]
    __hip_bfloat16* __restrict__ xproj)       // [512][32][64][4][16]
{
  __shared__ __align__(16) short aT[128 * 64];
  __shared__ __align__(16) short bT[128 * 64];
  const int tid = threadIdx.x, lane = tid & 63, wave = tid >> 6;
  const int m0 = blockIdx.y * 128, n0 = blockIdx.x * 128;
  const int wr = wave >> 1, wc = wave & 1;

  f32x4 acc[4][4] = {};

  for (int s = 0; s < 8; ++s) {               // K=512, BK=64
    __syncthreads();
    const int kbyte = s * 128;
#pragma unroll
    for (int it = 0; it < 4; ++it) {
      int flat = it * 256 + tid;
      int row = flat >> 3, gr = flat & 7;
      int sgr = gr ^ (row & 7);
      const char* ga = (const char*)xbf  + (size_t)(m0 + row) * 1024 + kbyte + sgr * 16;
      const char* gb = (const char*)wxbt + (size_t)(n0 + row) * 1024 + kbyte + sgr * 16;
      gload_lds16(ga, (char*)aT + (it * 256 + wave * 64) * 16);
      gload_lds16(gb, (char*)bT + (it * 256 + wave * 64) * 16);
    }
    __syncthreads();
#pragma unroll
    for (int kk2 = 0; kk2 < 2; ++kk2) {
      short8 af[4], bfr[4];
#pragma unroll
      for (int mt = 0; mt < 4; ++mt) {
        int r = wr * 64 + mt * 16 + (lane & 15);
        int g = (kk2 * 4 + (lane >> 4)) ^ (r & 7);
        af[mt] = *(const short8*)((const char*)aT + r * 128 + g * 16);
      }
#pragma unroll
      for (int nt = 0; nt < 4; ++nt) {
        int r = wc * 64 + nt * 16 + (lane & 15);
        int g = (kk2 * 4 + (lane >> 4)) ^ (r & 7);
        bfr[nt] = *(const short8*)((const char*)bT + r * 128 + g * 16);
      }
#pragma unroll
      for (int mt = 0; mt < 4; ++mt)
#pragma unroll
        for (int nt = 0; nt < 4; ++nt)
          acc[mt][nt] = __builtin_amdgcn_mfma_f32_16x16x32_bf16(af[mt], bfr[nt], acc[mt][nt], 0, 0, 0);
    }
  }
  // epilogue: + bias, store bf16 into re-laid layout. C: col=lane&15, row=(lane>>4)*4+i
#pragma unroll
  for (int nt = 0; nt < 4; ++nt) {
    int n = n0 + wc * 64 + nt * 16 + (lane & 15);
    float bv = bias[n];
    int j2 = (n >> 4) & 31, g2 = n >> 9, c2 = n & 15;
#pragma unroll
    for (int mt = 0; mt < 4; ++mt)
#pragma unroll
      for (int i = 0; i < 4; ++i) {
        int m = m0 + wr * 64 + mt * 16 + (lane >> 4) * 4 + i;
        int tt = m >> 6, rr = m & 63;
        xproj[(((size_t)tt * 32 + j2) * 64 + rr) * 64 + g2 * 16 + c2] =
            __float2bfloat16(acc[mt][nt][i] + bv);
      }
  }
}

// ---------------- phase 2: 128 independent waves (64-thread WGs).
// Wave bid: j = bid>>2 owns h-cols [j*16,j*16+16); w = bid&3 owns batch rows
// [w*16,w*16+16). hbuf32[2][64][512]: word = bf16(h) | tag<<16. Producer at step
// t stores tagged h (tag t+1) into buf[(t+1)&1], then flag (NO drain). Consumer
// at step t: poll flags[w*32+0..31] (packed, lanes 0-7), bulk-load slice,
// AND-validate tags (stale in {0,t-2} < t -> exact), chunked retry on rare miss.
__global__ __launch_bounds__(64, 1) void k_recur(
    const __hip_bfloat16* __restrict__ xproj, // [512][32][64][4][16]
    const __hip_bfloat16* __restrict__ whbt,  // [2048][512]
    unsigned* __restrict__ hbuf32,            // [2][64][512] tagged words
    float* __restrict__ out,                  // outputs | hx | cx
    int* __restrict__ flags)                  // [128], layout w*32+j
{
  __shared__ __align__(16) short wlds[64 * 512];   // 64 KB: row = g*16+c, swizzled
  const int lane = threadIdx.x;
  const int bid  = blockIdx.x;                 // 0..127
  const int j = bid >> 2, w = bid & 3;
  const int hc0 = j * 16, col = lane & 15, q = lane >> 4, mrow = q * 4;

  // ---- stage Wh into LDS once. LDS_phys[row][lane] = W[row][lane ^ (row&7)]
  // (involution). Read side XORs the same -> logical granule kk*4+q lands in
  // bank-group {(kk&1)^(col>>2&1), q^(col&3)}: 8 lanes per group, conflict-free.
  for (int it = 0; it < 64; ++it) {
    int sgr = lane ^ (it & 7);
    const char* gsrc = (const char*)whbt +
        ((size_t)((it >> 4) * 512 + hc0 + (it & 15))) * 1024 + sgr * 16;
    gload_lds16(gsrc, (char*)wlds + it * 1024);   // uniform base; HW adds lane*16
  }
  asm volatile("s_waitcnt vmcnt(0)" ::: "memory");
  __builtin_amdgcn_sched_barrier(0);           // no LDS read above the staging drain

  float c_state[4] = {0.f, 0.f, 0.f, 0.f};
  float* out_hx = out + (size_t)T_STEPS * BATCH * HDIM;
  float* out_cx = out_hx + BATCH * HDIM;

  // per-lane h chunk base: row = w*16 + (lane&15), words q*8.. (byte q*32)
  const char* hbl = (const char*)hbuf32 +
                    ((size_t)(w * 16 + (lane & 15)) * 512 + q * 8) * 4;
  const char* lrow = (const char*)wlds + (size_t)col * 1024;  // LDS row base (col part)
  const int   swl  = col & 7;

  for (int t = 0; t < T_STEPS; ++t) {
    const int cur = t & 1;
    // ---- xp loads pre-poll (drained by the poll/bulk vmcnt(0))
    const char* xpb = (const char*)xproj +
        (((size_t)t * 32 + j) * 4096 + (size_t)(w * 16 + mrow) * 64 + col) * 2;
    unsigned xpu[4][4];
#pragma unroll
    for (int g = 0; g < 4; ++g)
#pragma unroll
      for (int i = 0; i < 4; ++i) {
        const void* p = xpb + i * 128 + g * 32;
        asm volatile("global_load_ushort %0, %1, off"
                     : "=v"(xpu[g][i]) : "v"(p));
      }

    // ---- packed flag poll: lanes 0-7 each load 4 flags (dwordx4)
    if (t > 0 && lane < 8) {
      const int* fp = flags + w * 32 + lane * 4;
      int4v fv;
      do {
        asm volatile("global_load_dwordx4 %0, %1, off sc0 sc1\n\ts_waitcnt vmcnt(0)"
                     : "=v"(fv) : "v"(fp) : "memory");
      } while (fv[0] < t || fv[1] < t || fv[2] < t || fv[3] < t);
    }

    // ---- bulk h load (unconditional), single AND-validate; rare chunked retry
    const char* hb = hbl + (size_t)cur * (BATCH * HDIM * 4);
    int4v raw[32];
#pragma unroll
    for (int ii = 0; ii < 32; ++ii) {
      const void* p = hb + (size_t)(ii >> 1) * 128 + (ii & 1) * 16;
      asm volatile("global_load_dwordx4 %0, %1, off sc0 sc1"
                   : "=v"(raw[ii]) : "v"(p) : "memory");
    }
    asm volatile("s_waitcnt vmcnt(0)" ::: "memory");
    __builtin_amdgcn_sched_barrier(0);   // rule #18: no tag check above the drain
    unsigned andv = 0xffffffffu;
#pragma unroll
    for (int ii = 0; ii < 32; ++ii)
      andv &= (unsigned)raw[ii][0] & (unsigned)raw[ii][1]
            & (unsigned)raw[ii][2] & (unsigned)raw[ii][3];
    if (__builtin_expect((andv >> 16) != (unsigned)t, 0)) {
      // slow path: per-chunk retry (flag outran some h store)
      unsigned pend = 0u;
#pragma unroll
      for (int ii = 0; ii < 32; ++ii) {
        unsigned a = (unsigned)raw[ii][0] & (unsigned)raw[ii][1]
                   & (unsigned)raw[ii][2] & (unsigned)raw[ii][3];
        if ((a >> 16) != (unsigned)t) pend |= (1u << ii);
      }
      while (pend) {
#pragma unroll
        for (int ii = 0; ii < 32; ++ii)
          if (pend & (1u << ii)) {
            const void* p = hb + (size_t)(ii >> 1) * 128 + (ii & 1) * 16;
            asm volatile("global_load_dwordx4 %0, %1, off sc0 sc1"
                         : "=v"(raw[ii]) : "v"(p) : "memory");
          }
        asm volatile("s_waitcnt vmcnt(0)" ::: "memory");
        __builtin_amdgcn_sched_barrier(0);
#pragma unroll
        for (int ii = 0; ii < 32; ++ii)
          if (pend & (1u << ii)) {
            unsigned a = (unsigned)raw[ii][0] & (unsigned)raw[ii][1]
                       & (unsigned)raw[ii][2] & (unsigned)raw[ii][3];
            if ((a >> 16) == (unsigned)t) pend &= ~(1u << ii);
          }
      }
    }
    __builtin_amdgcn_sched_barrier(0);

    // ---- unpack tagged words -> A fragments; B from LDS (swizzled); MFMA
    f32x4 acc[4] = {};
#pragma unroll
    for (int kk = 0; kk < 16; ++kk) {
      int4v afw;
      afw[0] = (raw[2*kk][0]   & 0xffff) | (raw[2*kk][1]   << 16);
      afw[1] = (raw[2*kk][2]   & 0xffff) | (raw[2*kk][3]   << 16);
      afw[2] = (raw[2*kk+1][0] & 0xffff) | (raw[2*kk+1][1] << 16);
      afw[3] = (raw[2*kk+1][2] & 0xffff) | (raw[2*kk+1][3] << 16);
      short8 af = __builtin_bit_cast(short8, afw);
      int gsw = ((kk << 2) | q) ^ swl;
      const char* lk = lrow + (gsw << 4);
#pragma unroll
      for (int gg = 0; gg < 4; ++gg) {
        short8 bw = *(const short8*)(lk + gg * 16384);
        acc[gg] = __builtin_amdgcn_mfma_f32_16x16x32_bf16(af, bw, acc[gg], 0, 0, 0);
      }
    }

    // ---- epilogue: gates, state update
    float hnv[4], cnv[4];
#pragma unroll
    for (int i = 0; i < 4; ++i) {
      float pf = acc[0][i] + bf2f(xpu[0][i]);
      float pi = acc[1][i] + bf2f(xpu[1][i]);
      float pg = acc[2][i] + bf2f(xpu[2][i]);
      float po = acc[3][i] + bf2f(xpu[3][i]);
      float fg = sigf(pf), ig = sigf(pi), gg2 = tanh_fast(pg), og = sigf(po);
      float cn = fg * c_state[i] + ig * gg2;
      c_state[i] = cn;
      cnv[i] = cn;
      hnv[i] = og * tanh_fast(cn);
    }
    // ---- tagged h stores, then flag store: NO drain (tags validate order)
    if (t < T_STEPS - 1) {
      char* hnxt = (char*)hbuf32 + (size_t)(cur ^ 1) * (BATCH * HDIM * 4) +
                   ((size_t)(w * 16 + mrow) * 512 + hc0 + col) * 4;
      unsigned tag = ((unsigned)(t + 1)) << 16;
#pragma unroll
      for (int i = 0; i < 4; ++i) {
        unsigned word = bfbits(hnv[i]) | tag;
        void* p = hnxt + (size_t)i * 2048;
        asm volatile("global_store_dword %0, %1, off sc0 sc1"
                     :: "v"(p), "v"(word) : "memory");
      }
      if (lane == 0) {
        int nv = t + 1;
        int* fp2 = flags + w * 32 + j;
        asm volatile("global_store_dword %0, %1, off sc0 sc1"
                     :: "v"(fp2), "v"(nv) : "memory");
      }
    }
    // ---- out stores (plain, L2-ack; drained overlapped with next poll)
    float* outb = out + ((size_t)t * BATCH + w * 16 + mrow) * HDIM + hc0 + col;
#pragma unroll
    for (int i = 0; i < 4; ++i) outb[(size_t)i * HDIM] = hnv[i];
    if (t == T_STEPS - 1) {
#pragma unroll
      for (int i = 0; i < 4; ++i) {
        out_hx[(size_t)(w * 16 + mrow + i) * HDIM + hc0 + col] = hnv[i];
        out_cx[(size_t)(w * 16 + mrow + i) * HDIM + hc0 + col] = cnv[i];
      }
    }
  }
}

extern "C" void kernel_launch(void* const* d_in, const int* in_sizes, int n_in,
                              void* d_out, int out_size, void* d_ws, size_t ws_size,
                              hipStream_t stream) {
  const float* x   = (const float*)d_in[0];
  const float* Wf  = (const float*)d_in[1];
  const float* bf_ = (const float*)d_in[2];
  const float* Wi  = (const float*)d_in[3];
  const float* bi  = (const float*)d_in[4];
  const float* Wg  = (const float*)d_in[5];
  const float* bg  = (const float*)d_in[6];
  const float* Wo  = (const float*)d_in[7];
  const float* bo  = (const float*)d_in[8];

  char* ws = (char*)d_ws;
  __hip_bfloat16* xbf   = (__hip_bfloat16*)(ws);                 // 33,554,432 B
  __hip_bfloat16* wxbt  = (__hip_bfloat16*)(ws + 33554432);      //  2,097,152 B
  __hip_bfloat16* whbt  = (__hip_bfloat16*)(ws + 35651584);      //  2,097,152 B
  float*          bias  = (float*)         (ws + 37748736);      //      8,192 B
  __hip_bfloat16* xproj = (__hip_bfloat16*)(ws + 37756928);      // 134,217,728 B
  unsigned*       hbuf32= (unsigned*)      (ws + 171974656);     //    262,144 B
  int*            flags = (int*)           (ws + 172236800);     //        512 B

  k_prep <<<4096, 256, 0, stream>>>(Wf, bf_, Wi, bi, Wg, bg, Wo, bo,
                                    wxbt, whbt, bias, hbuf32, flags);
  k_convx<<<8192, 256, 0, stream>>>(x, xbf);
  k_xproj<<<dim3(16, 256), 256, 0, stream>>>(xbf, wxbt, bias, xproj);
  k_recur<<<128, 64, 0, stream>>>(xproj, whbt, hbuf32, (float*)d_out, flags);
}

// Round 10
// 1690.634 us; speedup vs baseline: 1.7064x; 1.3391x over previous
//
#include <hip/hip_runtime.h>
#include <hip/hip_bf16.h>
#include <stdint.h>
#include <stddef.h>

// LSTM: T=512, B=64, I=512, H=512.
// Phase 1: xproj GEMM (bf16 MFMA), output re-laid as [t][j=32][row=64][g=4][c=16].
// Phase 2: 128 independent waves (32 col-groups x 4 row-groups), 64-thr WGs.
//   R10 = R6 champion skeleton (system-scope sc0 sc1; flags[w*32+j]; producer
//   drains h-stores BEFORE flag -- R9 proved no-drain reorders; weights/xp
//   reloaded per step via plain loads pre-poll, off critical path; no LDS, no
//   tags) + two surgical latency plays:
//   (a) 2-deep pipelined flag poll: two poll loads in flight, check older
//       under vmcnt(1) -> catch delay ~0.5 RT instead of ~1.5 RT,
//   (b) counted-vmcnt chunk consume: issue all 16 h loads, then per chunk
//       s_waitcnt vmcnt(15-kk) + sched_barrier + 4 MFMAs (T4 idiom) -> MFMA
//       overlaps the later chunks' flight (in-order retirement makes the
//       counted waits safe even with compiler-inserted B reloads in the FIFO).

#define T_STEPS 512
#define BATCH   64
#define HDIM    512

using short8 = __attribute__((ext_vector_type(8))) short;  // 8 bf16 (4 VGPR) MFMA operand
using f32x4  = __attribute__((ext_vector_type(4))) float;  // MFMA accumulator
using int4v  = __attribute__((ext_vector_type(4))) int;

__device__ __forceinline__ void gload_lds16(const void* g, void* l) {
  __builtin_amdgcn_global_load_lds((const __attribute__((address_space(1))) void*)g,
                                   (__attribute__((address_space(3))) void*)l, 16, 0, 0);
}
__device__ __forceinline__ float sigf(float x) { return 1.0f / (1.0f + __expf(-x)); }
__device__ __forceinline__ float tanh_fast(float x) {
  x = fminf(fmaxf(x, -15.0f), 15.0f);
  float e = __expf(2.0f * x);
  return (e - 1.0f) / (e + 1.0f);
}
__device__ __forceinline__ short bfb(float f) {
  __hip_bfloat16 h = __float2bfloat16(f);
  short s; __builtin_memcpy(&s, &h, 2); return s;
}
__device__ __forceinline__ unsigned bfbits(float f) {
  __hip_bfloat16 h = __float2bfloat16(f);
  unsigned short s; __builtin_memcpy(&s, &h, 2); return (unsigned)s;
}
__device__ __forceinline__ float bf2f(unsigned u) {  // bf16 bits (low 16) -> f32
  return __builtin_bit_cast(float, u << 16);
}

// ---------------- prep: build Wx_bt/Wh_bt [2048][512] bf16, bias[2048], zero hbuf+flags
__global__ __launch_bounds__(256) void k_prep(
    const float* __restrict__ Wf, const float* __restrict__ bf_,
    const float* __restrict__ Wi, const float* __restrict__ bi,
    const float* __restrict__ Wg, const float* __restrict__ bg,
    const float* __restrict__ Wo, const float* __restrict__ bo,
    __hip_bfloat16* __restrict__ wxbt, __hip_bfloat16* __restrict__ whbt,
    float* __restrict__ bias, __hip_bfloat16* __restrict__ hbuf, int* __restrict__ flags)
{
  int idx = blockIdx.x * 256 + threadIdx.x;   // 4096 blocks -> 1,048,576 = 2048*512
  int row = idx >> 9;                          // 0..2047 (gate-major)
  int k   = idx & 511;
  int g = row >> 9, r = row & 511;
  const float* W = (g == 0) ? Wf : (g == 1) ? Wi : (g == 2) ? Wg : Wo;
  const float* B = (g == 0) ? bf_ : (g == 1) ? bi : (g == 2) ? bg : bo;
  wxbt[(size_t)row * 512 + k] = __float2bfloat16(W[(size_t)r * 1024 + k]);
  whbt[(size_t)row * 512 + k] = __float2bfloat16(W[(size_t)r * 1024 + 512 + k]);
  if (k == 0) bias[row] = B[r];
  if (idx < 2 * BATCH * HDIM) hbuf[idx] = __float2bfloat16(0.0f);  // both h buffers
  if (idx < 128) flags[idx] = 0;
}

// ---------------- convert x to bf16, 8 elems/thread
__global__ __launch_bounds__(256) void k_convx(const float* __restrict__ x,
                                               __hip_bfloat16* __restrict__ xbf)
{
  int idx = blockIdx.x * 256 + threadIdx.x;    // 8192 blocks
  const float4* p = (const float4*)x + (size_t)idx * 2;
  float4 a = p[0], b = p[1];
  short8 o;
  o[0]=bfb(a.x); o[1]=bfb(a.y); o[2]=bfb(a.z); o[3]=bfb(a.w);
  o[4]=bfb(b.x); o[5]=bfb(b.y); o[6]=bfb(b.z); o[7]=bfb(b.w);
  *(short8*)((short*)xbf + (size_t)idx * 8) = o;
}

// ---------------- phase 1 GEMM: [32768,512] x [512 -> 2048] (B^T layout), +bias
// Output re-laid: xproj[t][j][row][g][c]  (t=512, j=32 colgroups, row=64, g=4, c=16)
__global__ __launch_bounds__(256) void k_xproj(
    const __hip_bfloat16* __restrict__ xbf,   // [32768][512]
    const __hip_bfloat16* __restrict__ wxbt,  // [2048][512]
    const float* __restrict__ bias,           // [2048]
    __hip_bfloat16* __restrict__ xproj)       // [512][32][64][4][16]
{
  __shared__ __align__(16) short aT[128 * 64];
  __shared__ __align__(16) short bT[128 * 64];
  const int tid = threadIdx.x, lane = tid & 63, wave = tid >> 6;
  const int m0 = blockIdx.y * 128, n0 = blockIdx.x * 128;
  const int wr = wave >> 1, wc = wave & 1;

  f32x4 acc[4][4] = {};

  for (int s = 0; s < 8; ++s) {               // K=512, BK=64
    __syncthreads();
    const int kbyte = s * 128;
#pragma unroll
    for (int it = 0; it < 4; ++it) {
      int flat = it * 256 + tid;
      int row = flat >> 3, gr = flat & 7;
      int sgr = gr ^ (row & 7);
      const char* ga = (const char*)xbf  + (size_t)(m0 + row) * 1024 + kbyte + sgr * 16;
      const char* gb = (const char*)wxbt + (size_t)(n0 + row) * 1024 + kbyte + sgr * 16;
      gload_lds16(ga, (char*)aT + (it * 256 + wave * 64) * 16);
      gload_lds16(gb, (char*)bT + (it * 256 + wave * 64) * 16);
    }
    __syncthreads();
#pragma unroll
    for (int kk2 = 0; kk2 < 2; ++kk2) {
      short8 af[4], bfr[4];
#pragma unroll
      for (int mt = 0; mt < 4; ++mt) {
        int r = wr * 64 + mt * 16 + (lane & 15);
        int g = (kk2 * 4 + (lane >> 4)) ^ (r & 7);
        af[mt] = *(const short8*)((const char*)aT + r * 128 + g * 16);
      }
#pragma unroll
      for (int nt = 0; nt < 4; ++nt) {
        int r = wc * 64 + nt * 16 + (lane & 15);
        int g = (kk2 * 4 + (lane >> 4)) ^ (r & 7);
        bfr[nt] = *(const short8*)((const char*)bT + r * 128 + g * 16);
      }
#pragma unroll
      for (int mt = 0; mt < 4; ++mt)
#pragma unroll
        for (int nt = 0; nt < 4; ++nt)
          acc[mt][nt] = __builtin_amdgcn_mfma_f32_16x16x32_bf16(af[mt], bfr[nt], acc[mt][nt], 0, 0, 0);
    }
  }
  // epilogue: + bias, store bf16 into re-laid layout. C: col=lane&15, row=(lane>>4)*4+i
#pragma unroll
  for (int nt = 0; nt < 4; ++nt) {
    int n = n0 + wc * 64 + nt * 16 + (lane & 15);
    float bv = bias[n];
    int j2 = (n >> 4) & 31, g2 = n >> 9, c2 = n & 15;
#pragma unroll
    for (int mt = 0; mt < 4; ++mt)
#pragma unroll
      for (int i = 0; i < 4; ++i) {
        int m = m0 + wr * 64 + mt * 16 + (lane >> 4) * 4 + i;
        int tt = m >> 6, rr = m & 63;
        xproj[(((size_t)tt * 32 + j2) * 64 + rr) * 64 + g2 * 16 + c2] =
            __float2bfloat16(acc[mt][nt][i] + bv);
      }
  }
}

// ---------------- phase 2: 128 independent waves (64-thread WGs).
// Wave bid: j = bid>>2 owns h-cols [j*16,j*16+16); w = bid&3 owns batch rows
// [w*16,w*16+16). flags[w*32+j]. All cross-wave traffic via sc0 sc1 (LLC).
__global__ __launch_bounds__(64, 1) void k_recur(
    const __hip_bfloat16* __restrict__ xproj, // [512][32][64][4][16]
    const __hip_bfloat16* __restrict__ whbt,  // [2048][512]
    __hip_bfloat16* __restrict__ hbuf,        // [2][64][512]
    float* __restrict__ out,                  // outputs | hx | cx
    int* __restrict__ flags)                  // [128], layout w*32+j
{
  const int lane = threadIdx.x;
  const int bid  = blockIdx.x;                 // 0..127
  const int j = bid >> 2, w = bid & 3;
  const int hc0 = j * 16, col = lane & 15, q = lane >> 4, mrow = q * 4;

  float c_state[4] = {0.f, 0.f, 0.f, 0.f};
  float* out_hx = out + (size_t)T_STEPS * BATCH * HDIM;
  float* out_cx = out_hx + BATCH * HDIM;

  // invariant base for this wave's Wh slice: B[k][c]=whbt[g*512+hc0+c][k],
  // per lane c=lane&15, k=kk*32+q*8+0..7
  const char* wbase = (const char*)whbt + ((size_t)(hc0 + col)) * 1024 + q * 16;

  for (int t = 0; t < T_STEPS; ++t) {
    const int cur = t & 1;
    // ---- Wh slice loads: plain, L2-hot, issued BEFORE the poll so they fly
    // during the spin. "memory" clobbers below pin them here.
    short8 bw[16][4];
#pragma unroll
    for (int kk = 0; kk < 16; ++kk)
#pragma unroll
      for (int gg = 0; gg < 4; ++gg)
        bw[kk][gg] = *(const short8*)(wbase + (size_t)gg * 524288 + (size_t)kk * 64);

    // ---- xp loads, also pre-poll (drained by the pre-spin vmcnt(0))
    const char* xpb = (const char*)xproj +
        (((size_t)t * 32 + j) * 4096 + (size_t)(w * 16 + mrow) * 64 + col) * 2;
    unsigned xpu[4][4];
#pragma unroll
    for (int g = 0; g < 4; ++g)
#pragma unroll
      for (int i = 0; i < 4; ++i) {
        const void* p = xpb + i * 128 + g * 32;
        asm volatile("global_load_ushort %0, %1, off"
                     : "=v"(xpu[g][i]) : "v"(p) : "memory");
      }
    // ---- (a) 2-deep pipelined poll of own row-group's 32 flags.
    // First load + vmcnt(0) drains bw/xp too (overlapped with the spin).
    if (t > 0) {
      const int* fp = flags + w * 32 + (lane & 31);
      int f0, f1;
      asm volatile("global_load_dword %0, %1, off sc0 sc1" : "=v"(f0) : "v"(fp) : "memory");
      asm volatile("s_waitcnt vmcnt(0)" ::: "memory");
      if (f0 < t) {
        for (;;) {
          asm volatile("global_load_dword %0, %1, off sc0 sc1" : "=v"(f1) : "v"(fp) : "memory");
          asm volatile("s_waitcnt vmcnt(1)" ::: "memory");   // f0 complete
          if (f0 >= t) break;                                 // f1 still flying
          asm volatile("global_load_dword %0, %1, off sc0 sc1" : "=v"(f0) : "v"(fp) : "memory");
          asm volatile("s_waitcnt vmcnt(1)" ::: "memory");   // f1 complete
          if (f1 >= t) break;                                 // f0 still flying
        }
        asm volatile("s_waitcnt vmcnt(0)" ::: "memory");      // retire leftover poll
      }
    } else {
      asm volatile("s_waitcnt vmcnt(0)" ::: "memory");        // t=0: drain bw/xp
    }

    // ---- (b) issue all 16 h-chunk loads, consume with counted vmcnt.
    const char* hb = (const char*)hbuf + cur * (BATCH * HDIM * 2) +
                     (size_t)(w * 16 + (lane & 15)) * 1024 + q * 16;
    int4v araw[16];
#pragma unroll
    for (int kk = 0; kk < 16; ++kk) {
      const void* p = hb + kk * 64;
      asm volatile("global_load_dwordx4 %0, %1, off sc0 sc1"
                   : "=v"(araw[kk]) : "v"(p) : "memory");
    }
    f32x4 acc[4] = {};
#pragma unroll
    for (int kk = 0; kk < 16; ++kk) {
      asm volatile("s_waitcnt vmcnt(%0)" :: "i"(15 - kk) : "memory");  // chunk kk landed
      __builtin_amdgcn_sched_barrier(0);   // rule #18: MFMA stays below its wait
      short8 af = __builtin_bit_cast(short8, araw[kk]);
#pragma unroll
      for (int gg = 0; gg < 4; ++gg)
        acc[gg] = __builtin_amdgcn_mfma_f32_16x16x32_bf16(af, bw[kk][gg], acc[gg], 0, 0, 0);
    }

    // ---- epilogue: gates, state update (xpu drained pre-spin)
    float hnv[4], cnv[4];
#pragma unroll
    for (int i = 0; i < 4; ++i) {
      float pf = acc[0][i] + bf2f(xpu[0][i]);
      float pi = acc[1][i] + bf2f(xpu[1][i]);
      float pg = acc[2][i] + bf2f(xpu[2][i]);
      float po = acc[3][i] + bf2f(xpu[3][i]);
      float fg = sigf(pf), ig = sigf(pi), gg2 = tanh_fast(pg), og = sigf(po);
      float cn = fg * c_state[i] + ig * gg2;
      c_state[i] = cn;
      cnv[i] = cn;
      hnv[i] = og * tanh_fast(cn);
    }
    // ---- h stores -> drain -> flag publish (R6-proven order); out stores AFTER
    char* hnxt = (char*)hbuf + (cur ^ 1) * (BATCH * HDIM * 2) +
                 ((size_t)(w * 16 + mrow) * 512 + hc0 + col) * 2;
#pragma unroll
    for (int i = 0; i < 4; ++i) {
      unsigned hb16 = bfbits(hnv[i]);
      void* p = hnxt + i * 1024;
      asm volatile("global_store_short %0, %1, off sc0 sc1"
                   :: "v"(p), "v"(hb16) : "memory");
    }
    asm volatile("s_waitcnt vmcnt(0)" ::: "memory");  // h stores at LLC
    if (t < T_STEPS - 1 && lane == 0) {
      int nv = t + 1;
      int* fp2 = flags + w * 32 + j;
      asm volatile("global_store_dword %0, %1, off sc0 sc1"
                   :: "v"(fp2), "v"(nv) : "memory");
    }
    float* outb = out + ((size_t)t * BATCH + w * 16 + mrow) * HDIM + hc0 + col;
#pragma unroll
    for (int i = 0; i < 4; ++i) outb[(size_t)i * HDIM] = hnv[i];
    if (t == T_STEPS - 1) {
#pragma unroll
      for (int i = 0; i < 4; ++i) {
        out_hx[(size_t)(w * 16 + mrow + i) * HDIM + hc0 + col] = hnv[i];
        out_cx[(size_t)(w * 16 + mrow + i) * HDIM + hc0 + col] = cnv[i];
      }
    }
  }
}

extern "C" void kernel_launch(void* const* d_in, const int* in_sizes, int n_in,
                              void* d_out, int out_size, void* d_ws, size_t ws_size,
                              hipStream_t stream) {
  const float* x   = (const float*)d_in[0];
  const float* Wf  = (const float*)d_in[1];
  const float* bf_ = (const float*)d_in[2];
  const float* Wi  = (const float*)d_in[3];
  const float* bi  = (const float*)d_in[4];
  const float* Wg  = (const float*)d_in[5];
  const float* bg  = (const float*)d_in[6];
  const float* Wo  = (const float*)d_in[7];
  const float* bo  = (const float*)d_in[8];

  char* ws = (char*)d_ws;
  __hip_bfloat16* xbf   = (__hip_bfloat16*)(ws);                 // 33,554,432 B
  __hip_bfloat16* wxbt  = (__hip_bfloat16*)(ws + 33554432);      //  2,097,152 B
  __hip_bfloat16* whbt  = (__hip_bfloat16*)(ws + 35651584);      //  2,097,152 B
  float*          bias  = (float*)         (ws + 37748736);      //      8,192 B
  __hip_bfloat16* xproj = (__hip_bfloat16*)(ws + 37756928);      // 134,217,728 B
  __hip_bfloat16* hbuf  = (__hip_bfloat16*)(ws + 171974656);     //    131,072 B
  int*            flags = (int*)           (ws + 172105728);     //        512 B

  k_prep <<<4096, 256, 0, stream>>>(Wf, bf_, Wi, bi, Wg, bg, Wo, bo,
                                    wxbt, whbt, bias, hbuf, flags);
  k_convx<<<8192, 256, 0, stream>>>(x, xbf);
  k_xproj<<<dim3(16, 256), 256, 0, stream>>>(xbf, wxbt, bias, xproj);
  k_recur<<<128, 64, 0, stream>>>(xproj, whbt, hbuf, (float*)d_out, flags);
}